// Round 13
// baseline (653.242 us; speedup 1.0000x reference)
//
#include <hip/hip_runtime.h>

#define DIM 128
#define NLEV 8
#define NB_STAGE 512           // stage-kernel grid; 4 waves/block -> 2048 wave-slots
#define NSLOT (NB_STAGE * 4)
#define CAP (2 * NSLOT)        // max nodes per class handled (expected ~1213)

// packed-weight offsets (float2 units): [k][jl] -> (W[k][jl], W[k][jl+64])
#define AS_OFF 0
#define UA_OFF 8192            // 256 rows -> 16384 float2
#define NS_OFF 24576
#define UN_OFF 32768
#define PACK_TOTAL 40960

__device__ __forceinline__ int cls_of(int g, int l) {
    if (l < 1 || l > NLEV) return -1;
    if (g == 1) return l - 1;
    if (g == 2) return NLEV + (l - 1);
    return -1;
}

// ---------------- prep kernels ----------------

__global__ void deg_count_kernel(const int* __restrict__ dstv, int* __restrict__ degi, int E) {
    int i = blockIdx.x * blockDim.x + threadIdx.x;
    if (i < E) atomicAdd(&degi[dstv[i]], 1);
}

// pack 4 stage weight matrices into float2-paired layout (coalesced dwordx2 reads)
__global__ void pack_kernel(const float* __restrict__ as_w, const float* __restrict__ ua_w,
                            const float* __restrict__ ns_w, const float* __restrict__ un_w,
                            float2* __restrict__ wpack) {
    int i = blockIdx.x * 256 + threadIdx.x;
    if (i >= PACK_TOTAL) return;
    const float* src;
    int local;
    if (i < UA_OFF)      { src = as_w; local = i; }
    else if (i < NS_OFF) { src = ua_w; local = i - UA_OFF; }
    else if (i < UN_OFF) { src = ns_w; local = i - NS_OFF; }
    else                 { src = un_w; local = i - UN_OFF; }
    int k = local >> 6, jl = local & 63;
    wpack[i] = make_float2(src[k * DIM + jl], src[k * DIM + jl + 64]);
}

// b' = gcn_b @ mu_w + mu_b   (folded GCN bias)
__global__ __launch_bounds__(DIM) void bprime_kernel(const float* __restrict__ gcn_b,
                                                     const float* __restrict__ mu_w,
                                                     const float* __restrict__ mu_b,
                                                     float* __restrict__ bp) {
    const int j = threadIdx.x;
    float acc = mu_b[j];
    for (int k = 0; k < DIM; k++) acc = fmaf(gcn_b[k], mu_w[k * DIM + j], acc);
    bp[j] = acc;
}

// ---- 3-kernel parallel exclusive scan (+ fused deg finalize) ----
__global__ __launch_bounds__(1024) void scan1_kernel(const int* __restrict__ degi,
                                                     int* __restrict__ offs,
                                                     int* __restrict__ bsum,
                                                     float* __restrict__ dis,
                                                     float* __restrict__ inv) {
    __shared__ int sh[1024];
    const int gid = blockIdx.x * 1024 + threadIdx.x;
    const int v = degi[gid];
    {
        float d = (float)v + 1.0f;
        dis[gid] = rsqrtf(d);
        inv[gid] = 1.0f / d;
    }
    sh[threadIdx.x] = v;
    __syncthreads();
    for (int off = 1; off < 1024; off <<= 1) {
        int t = (threadIdx.x >= off) ? sh[threadIdx.x - off] : 0;
        __syncthreads();
        sh[threadIdx.x] += t;
        __syncthreads();
    }
    offs[gid] = sh[threadIdx.x] - v;  // exclusive within block
    if (threadIdx.x == 1023) bsum[blockIdx.x] = sh[1023];
}

__global__ void scan2_kernel(int* __restrict__ bsum, int nb) {
    const int lane = threadIdx.x & 63;
    const int orig = (lane < nb) ? bsum[lane] : 0;
    int v = orig;
#pragma unroll
    for (int off = 1; off < 64; off <<= 1) {
        int t = __shfl_up(v, off, 64);
        if (lane >= off) v += t;
    }
    if (lane < nb) bsum[lane] = v - orig;  // exclusive base per block
    if (lane == nb - 1) bsum[nb] = v;      // grand total
}

__global__ __launch_bounds__(1024) void scan3_kernel(int* __restrict__ offs,
                                                     const int* __restrict__ bsum, int n) {
    const int gid = blockIdx.x * 1024 + threadIdx.x;
    offs[gid] += bsum[blockIdx.x];
    if (gid == n - 1) offs[n] = bsum[gridDim.x];
}

__global__ void csr_fill_kernel(const int* __restrict__ srcv, const int* __restrict__ dstv,
                                const int* __restrict__ offs, int* __restrict__ cursor,
                                int* __restrict__ csr_src, int E) {
    int i = blockIdx.x * blockDim.x + threadIdx.x;
    if (i >= E) return;
    int d = dstv[i];
    int pos = offs[d] + atomicAdd(&cursor[d], 1);
    csr_src[pos] = srcv[i];
}

// class lists + per-node packed (cls<<16)|idx lookup (clsidx pre-memset to -1)
__global__ __launch_bounds__(256) void build_node_lists_kernel(const int* __restrict__ gate,
                                                               const int* __restrict__ level,
                                                               int* __restrict__ nlist,
                                                               int* __restrict__ ncnt,
                                                               int* __restrict__ clsidx, int n) {
    __shared__ int lcnt[16];
    __shared__ int lbase[16];
    int t = threadIdx.x;
    int i = blockIdx.x * 256 + t;
    if (t < 16) lcnt[t] = 0;
    __syncthreads();
    int c = -1, lpos = 0;
    if (i < n) {
        c = cls_of(gate[i], level[i]);
        if (c >= 0) lpos = atomicAdd(&lcnt[c], 1);
    }
    __syncthreads();
    if (t < 16 && lcnt[t] > 0) lbase[t] = atomicAdd(&ncnt[t], lcnt[t]);
    __syncthreads();
    if (c >= 0) {
        int idx = lbase[c] + lpos;
        nlist[c * n + idx] = i;
        clsidx[i] = (c << 16) | idx;
    }
}

// ---------------- dense matmul: LDS-staged input tile, 32 rows/block ----------------
template <int BIAS>
__global__ __launch_bounds__(256) void mm_kernel(const float* __restrict__ in0,
                                                 const float* __restrict__ W,
                                                 const float* __restrict__ b,
                                                 float* __restrict__ out, int n) {
    const int R = 32;
    __shared__ float tile[R * DIM];
    const size_t row0 = (size_t)blockIdx.x * R;
    for (int t = threadIdx.x; t < R * DIM / 4; t += 256)
        ((float4*)tile)[t] = ((const float4*)(in0 + row0 * DIM))[t];
    __syncthreads();
    const int g = threadIdx.x >> 7;   // row-half 0/1
    const int j = threadIdx.x & 127;  // output column
    float acc[16];
#pragma unroll
    for (int r = 0; r < 16; r++) acc[r] = 0.f;
    const float* tb = tile + (g * 16) * DIM;
    for (int k = 0; k < DIM; k += 4) {
        float w0 = W[(k + 0) * DIM + j];
        float w1 = W[(k + 1) * DIM + j];
        float w2 = W[(k + 2) * DIM + j];
        float w3 = W[(k + 3) * DIM + j];
#pragma unroll
        for (int r = 0; r < 16; r++) {
            const float4 a = *reinterpret_cast<const float4*>(tb + r * DIM + k);
            acc[r] = fmaf(a.x, w0, acc[r]);
            acc[r] = fmaf(a.y, w1, acc[r]);
            acc[r] = fmaf(a.z, w2, acc[r]);
            acc[r] = fmaf(a.w, w3, acc[r]);
        }
    }
    float bias = BIAS ? b[j] : 0.f;
#pragma unroll
    for (int r = 0; r < 16; r++) out[(row0 + g * 16 + r) * DIM + j] = acc[r] + bias;
}

// fused decoder matmul: zs = in0 @ Ws, zt = in0 @ Wt (shared tile stage)
__global__ __launch_bounds__(256) void mm2_kernel(const float* __restrict__ in0,
                                                  const float* __restrict__ Ws,
                                                  const float* __restrict__ Wt,
                                                  float* __restrict__ zs,
                                                  float* __restrict__ zt, int n) {
    const int R = 32;
    __shared__ float tile[R * DIM];
    const size_t row0 = (size_t)blockIdx.x * R;
    for (int t = threadIdx.x; t < R * DIM / 4; t += 256)
        ((float4*)tile)[t] = ((const float4*)(in0 + row0 * DIM))[t];
    __syncthreads();
    const int g = threadIdx.x >> 7;
    const int j = threadIdx.x & 127;
    float accs[16], acct[16];
#pragma unroll
    for (int r = 0; r < 16; r++) { accs[r] = 0.f; acct[r] = 0.f; }
    const float* tb = tile + (g * 16) * DIM;
    for (int k = 0; k < DIM; k += 2) {
        float s0 = Ws[(k + 0) * DIM + j];
        float s1 = Ws[(k + 1) * DIM + j];
        float t0 = Wt[(k + 0) * DIM + j];
        float t1 = Wt[(k + 1) * DIM + j];
#pragma unroll
        for (int r = 0; r < 16; r++) {
            const float2 a = *reinterpret_cast<const float2*>(tb + r * DIM + k);
            accs[r] = fmaf(a.x, s0, accs[r]);
            accs[r] = fmaf(a.y, s1, accs[r]);
            acct[r] = fmaf(a.x, t0, acct[r]);
            acct[r] = fmaf(a.y, t1, acct[r]);
        }
    }
#pragma unroll
    for (int r = 0; r < 16; r++) {
        zs[(row0 + g * 16 + r) * DIM + j] = accs[r];
        zt[(row0 + g * 16 + r) * DIM + j] = acct[r];
    }
}

// ---------------- GCN aggregate as gather (bias folded into b') ----------------
__global__ __launch_bounds__(256) void gcn_gather_kernel(const float* __restrict__ x,
                                                         const float* __restrict__ dis,
                                                         const float* __restrict__ inv,
                                                         const int* __restrict__ offs,
                                                         const int* __restrict__ csr_src,
                                                         float* __restrict__ y, int n) {
    int slot = threadIdx.x >> 7, j = threadIdx.x & 127;
    for (int node = blockIdx.x * 2 + slot; node < n; node += gridDim.x * 2) {
        float di = dis[node];
        float acc = inv[node] * x[(size_t)node * DIM + j];
        int e1 = offs[node + 1];
        for (int p = offs[node]; p < e1; p++) {
            int s = csr_src[p];
            acc += di * dis[s] * x[(size_t)s * DIM + j];
        }
        y[(size_t)node * DIM + j] = acc;
    }
}

// ---------------- level-stage kernels: wave-per-node, W read from L2 (global) ----------------

template <bool MERGE>
__device__ __forceinline__ const float* resolve_row(const float* __restrict__ base,
                                                    const float* __restrict__ tmp,
                                                    const int* __restrict__ clsidx,
                                                    int mcls, int s) {
    if (MERGE) {
        int cc = clsidx[s];
        if ((cc >> 16) == mcls && (cc & 0xFFFF) < CAP) return tmp + (size_t)(cc & 0xFFFF) * DIM;
    }
    return base + (size_t)s * DIM;
}

// wave gathers sum over in-edges of relu(row(src) @ W + b); 2-edge unroll.
// W2 points at packed weights in GLOBAL memory (L2-resident, shared by all blocks).
template <bool MERGE>
__device__ __forceinline__ void gather_node(const float* __restrict__ hs,
                                            const float* __restrict__ tmp,
                                            const int* __restrict__ clsidx, int mcls,
                                            const float2* __restrict__ W2,
                                            float bj0, float bj1,
                                            const int* __restrict__ csr_src,
                                            int e0, int e1, int lane,
                                            float& acc0, float& acc1) {
    for (int p = e0; p < e1; p += 2) {
        const bool two = (p + 1 < e1);
        const int s0 = csr_src[p];
        const int s1 = two ? csr_src[p + 1] : s0;
        const float* r0 = resolve_row<MERGE>(hs, tmp, clsidx, mcls, s0);
        const float* r1 = resolve_row<MERGE>(hs, tmp, clsidx, mcls, s1);
        float a00 = r0[lane], a01 = r0[lane + 64];
        float a10 = r1[lane], a11 = r1[lane + 64];
        float m00 = bj0, m01 = bj1, m10 = bj0, m11 = bj1;
#pragma unroll 8
        for (int k = 0; k < 64; k++) {
            float2 w = W2[k * 64 + lane];
            float v0 = __shfl(a00, k, 64);
            float v1 = __shfl(a10, k, 64);
            m00 = fmaf(v0, w.x, m00); m01 = fmaf(v0, w.y, m01);
            m10 = fmaf(v1, w.x, m10); m11 = fmaf(v1, w.y, m11);
        }
#pragma unroll 8
        for (int k = 0; k < 64; k++) {
            float2 w = W2[(k + 64) * 64 + lane];
            float v0 = __shfl(a01, k, 64);
            float v1 = __shfl(a11, k, 64);
            m00 = fmaf(v0, w.x, m00); m01 = fmaf(v0, w.y, m01);
            m10 = fmaf(v1, w.x, m10); m11 = fmaf(v1, w.y, m11);
        }
        acc0 += fmaxf(m00, 0.f);
        acc1 += fmaxf(m01, 0.f);
        if (two) { acc0 += fmaxf(m10, 0.f); acc1 += fmaxf(m11, 0.f); }
    }
}

// AND stage: commit tmpN(cNp)->hs ; agg = gather(as_w, merged w/ tmpN) ;
//            tmpA[idx] = relu( cat[hs[node], agg] @ ua_w + ua_b )
// No LDS, no barriers: W comes from L2; commit/gather race prevented by tmp-indirection.
template <bool MERGE>
__global__ __launch_bounds__(256) void and_stage_kernel(
        float* __restrict__ hs, const float* __restrict__ tmpN, float* __restrict__ tmpA,
        const int* __restrict__ offs, const int* __restrict__ csr_src,
        const int* __restrict__ nlist, const int* __restrict__ ncnt,
        const int* __restrict__ clsidx, const float2* __restrict__ wpack,
        const float* __restrict__ as_b, const float* __restrict__ ua_b,
        int cA, int cNp, int n) {
    const int cnt = min(ncnt[cA], CAP);
    const int cntp = MERGE ? min(ncnt[cNp], CAP) : 0;
    const int lim = max(cnt, cntp);
    if ((int)blockIdx.x * 4 >= lim) return;  // block-uniform early exit
    const int lane = threadIdx.x & 63;
    const int gslot = (blockIdx.x << 2) | (threadIdx.x >> 6);
    if (MERGE) {
        for (int idx = gslot; idx < cntp; idx += NSLOT) {
            const int node = nlist[cNp * n + idx];
            hs[(size_t)node * DIM + lane] = tmpN[(size_t)idx * DIM + lane];
            hs[(size_t)node * DIM + lane + 64] = tmpN[(size_t)idx * DIM + lane + 64];
        }
    }
    const float bj_as0 = as_b[lane], bj_as1 = as_b[lane + 64];
    const float2* Was = wpack + AS_OFF;
    const float2* Wua = wpack + UA_OFF;
#pragma unroll
    for (int it = 0; it < 2; it++) {
        const int idx = gslot + it * NSLOT;
        if (idx >= cnt) break;
        const int nd = nlist[cA * n + idx];
        float ag0 = 0.f, ag1 = 0.f;
        gather_node<MERGE>(hs, tmpN, clsidx, cNp, Was, bj_as0, bj_as1, csr_src,
                           offs[nd], offs[nd + 1], lane, ag0, ag1);
        // cA rows are not written by anyone this kernel -> pre-update value, as required
        const float h0 = hs[(size_t)nd * DIM + lane];
        const float h1 = hs[(size_t)nd * DIM + lane + 64];
        float u0 = ua_b[lane], u1 = ua_b[lane + 64];
#pragma unroll 8
        for (int k = 0; k < 64; k++) {            // ua_w rows 0..63 (hs lo half)
            float2 w = Wua[k * 64 + lane];
            float v = __shfl(h0, k, 64);
            u0 = fmaf(v, w.x, u0); u1 = fmaf(v, w.y, u1);
        }
#pragma unroll 8
        for (int k = 0; k < 64; k++) {            // ua_w rows 64..127 (hs hi half)
            float2 w = Wua[(k + 64) * 64 + lane];
            float v = __shfl(h1, k, 64);
            u0 = fmaf(v, w.x, u0); u1 = fmaf(v, w.y, u1);
        }
#pragma unroll 8
        for (int k = 0; k < 64; k++) {            // ua_w rows 128..191 (agg lo half)
            float2 w = Wua[(k + 128) * 64 + lane];
            float v = __shfl(ag0, k, 64);
            u0 = fmaf(v, w.x, u0); u1 = fmaf(v, w.y, u1);
        }
#pragma unroll 8
        for (int k = 0; k < 64; k++) {            // ua_w rows 192..255 (agg hi half)
            float2 w = Wua[(k + 192) * 64 + lane];
            float v = __shfl(ag1, k, 64);
            u0 = fmaf(v, w.x, u0); u1 = fmaf(v, w.y, u1);
        }
        tmpA[(size_t)idx * DIM + lane] = fmaxf(u0, 0.f);
        tmpA[(size_t)idx * DIM + lane + 64] = fmaxf(u1, 0.f);
    }
}

// NOT stage: commit tmpA(cA)->hs ; agg = gather(ns_w, merged w/ tmpA) ;
//            tmpN[idx] = tanh( agg @ un_w + un_b )
__global__ __launch_bounds__(256) void not_stage_kernel(
        float* __restrict__ hs, const float* __restrict__ tmpA, float* __restrict__ tmpN,
        const int* __restrict__ offs, const int* __restrict__ csr_src,
        const int* __restrict__ nlist, const int* __restrict__ ncnt,
        const int* __restrict__ clsidx, const float2* __restrict__ wpack,
        const float* __restrict__ ns_b, const float* __restrict__ un_b,
        int cA, int cN, int n) {
    const int cnt = min(ncnt[cN], CAP);
    const int cntA = min(ncnt[cA], CAP);
    const int lim = max(cnt, cntA);
    if ((int)blockIdx.x * 4 >= lim) return;
    const int lane = threadIdx.x & 63;
    const int gslot = (blockIdx.x << 2) | (threadIdx.x >> 6);
    for (int idx = gslot; idx < cntA; idx += NSLOT) {
        const int node = nlist[cA * n + idx];
        hs[(size_t)node * DIM + lane] = tmpA[(size_t)idx * DIM + lane];
        hs[(size_t)node * DIM + lane + 64] = tmpA[(size_t)idx * DIM + lane + 64];
    }
    const float bj_ns0 = ns_b[lane], bj_ns1 = ns_b[lane + 64];
    const float2* Wns = wpack + NS_OFF;
    const float2* Wun = wpack + UN_OFF;
#pragma unroll
    for (int it = 0; it < 2; it++) {
        const int idx = gslot + it * NSLOT;
        if (idx >= cnt) break;
        const int nd = nlist[cN * n + idx];
        float ag0 = 0.f, ag1 = 0.f;
        gather_node<true>(hs, tmpA, clsidx, cA, Wns, bj_ns0, bj_ns1, csr_src,
                          offs[nd], offs[nd + 1], lane, ag0, ag1);
        float u0 = un_b[lane], u1 = un_b[lane + 64];
#pragma unroll 8
        for (int k = 0; k < 64; k++) {
            float2 w = Wun[k * 64 + lane];
            float v = __shfl(ag0, k, 64);
            u0 = fmaf(v, w.x, u0); u1 = fmaf(v, w.y, u1);
        }
#pragma unroll 8
        for (int k = 0; k < 64; k++) {
            float2 w = Wun[(k + 64) * 64 + lane];
            float v = __shfl(ag1, k, 64);
            u0 = fmaf(v, w.x, u0); u1 = fmaf(v, w.y, u1);
        }
        tmpN[(size_t)idx * DIM + lane] = tanhf(u0);
        tmpN[(size_t)idx * DIM + lane + 64] = tanhf(u1);
    }
}

// final commit of last level's tmpN -> hs
__global__ __launch_bounds__(256) void commit_kernel(float* __restrict__ hs,
                                                     const float* __restrict__ tmp,
                                                     const int* __restrict__ nlist,
                                                     const int* __restrict__ ncnt,
                                                     int c, int n) {
    const int lane = threadIdx.x & 63;
    const int gslot = (blockIdx.x << 2) | (threadIdx.x >> 6);
    const int cnt = min(ncnt[c], CAP);
    for (int idx = gslot; idx < cnt; idx += NSLOT) {
        const int node = nlist[c * n + idx];
        hs[(size_t)node * DIM + lane] = tmp[(size_t)idx * DIM + lane];
        hs[(size_t)node * DIM + lane + 64] = tmp[(size_t)idx * DIM + lane + 64];
    }
}

// ---------------- decoder as gather (wave per node, deterministic) ----------------
__global__ __launch_bounds__(256) void dec_gather_kernel(const float* __restrict__ zs,
                                                         const float* __restrict__ zt,
                                                         const int* __restrict__ offs,
                                                         const int* __restrict__ csr_src,
                                                         float* __restrict__ hf_out, int n) {
    int w = threadIdx.x >> 6, lane = threadIdx.x & 63;
    for (int node = blockIdx.x * 4 + w; node < n; node += gridDim.x * 4) {
        float b0 = zt[(size_t)node * DIM + lane];
        float b1 = zt[(size_t)node * DIM + 64 + lane];
        float acc0 = 0.f, acc1 = 0.f;
        int e1 = offs[node + 1];
        for (int p = offs[node]; p < e1; p++) {
            int s = csr_src[p];
            float a0 = zs[(size_t)s * DIM + lane];
            float a1 = zs[(size_t)s * DIM + 64 + lane];
            float pd = a0 * b0 + a1 * b1;
#pragma unroll
            for (int off = 32; off > 0; off >>= 1) pd += __shfl_xor(pd, off, 64);
            float wg = 1.f / (1.f + __expf(-pd));
            acc0 += wg * a0;
            acc1 += wg * a1;
        }
        hf_out[(size_t)node * DIM + lane] = acc0;
        hf_out[(size_t)node * DIM + 64 + lane] = acc1;
    }
}

extern "C" void kernel_launch(void* const* d_in, const int* in_sizes, int n_in,
                              void* d_out, int out_size, void* d_ws, size_t ws_size,
                              hipStream_t stream) {
    const float* hs_init = (const float*)d_in[0];
    const int* ei = (const int*)d_in[1];
    const int* gate = (const int*)d_in[2];
    const int* level = (const int*)d_in[3];
    const float* gcn_w = (const float*)d_in[4];
    const float* gcn_b = (const float*)d_in[5];
    const float* mu_w = (const float*)d_in[6];
    const float* mu_b = (const float*)d_in[7];
    // ls_w/ls_b (8,9) dead (eval mode); af/nf (14..17) dead (level-loop hf never feeds hs;
    // decoder rebuilds hf from hs alone).
    const float* as_w = (const float*)d_in[10];
    const float* as_b = (const float*)d_in[11];
    const float* ns_w = (const float*)d_in[12];
    const float* ns_b = (const float*)d_in[13];
    const float* ua_w = (const float*)d_in[18];
    const float* ua_b = (const float*)d_in[19];
    const float* un_w = (const float*)d_in[20];
    const float* un_b = (const float*)d_in[21];
    const float* dec_ws_w = (const float*)d_in[22];
    const float* dec_wt_w = (const float*)d_in[23];

    const int n = in_sizes[0] / DIM;  // 32768
    const int E = in_sizes[1] / 2;    // 65536
    const int* srcv = ei;
    const int* dstv = ei + E;

    float* hs = (float*)d_out;             // [n, DIM]
    float* hf_out = hs + (size_t)n * DIM;  // [n, DIM]

    char* wp = (char*)d_ws;
    float* x = (float*)wp;      wp += (size_t)n * DIM * 4;     // gcn agg, later zs
    float* x2 = (float*)wp;     wp += (size_t)n * DIM * 4;     // zt
    float* tmpA = (float*)wp;   wp += (size_t)CAP * DIM * 4;   // AND-update staging
    float* tmpN = (float*)wp;   wp += (size_t)CAP * DIM * 4;   // NOT-update staging
    float2* wpack = (float2*)wp; wp += (size_t)PACK_TOTAL * 8; // packed stage weights
    float* wprime = (float*)wp; wp += (size_t)DIM * DIM * 4;   // gcn_w @ mu_w
    float* bprime = (float*)wp; wp += (size_t)DIM * 4;         // gcn_b @ mu_w + mu_b
    char* small0 = wp;
    int* degi = (int*)wp;   wp += (size_t)n * 4;
    int* cursor = (int*)wp; wp += (size_t)n * 4;
    int* ncnt = (int*)wp;   wp += 16 * 4;
    size_t small_bytes = (size_t)(wp - small0);
    int* bsum = (int*)wp;    wp += 64 * 4;
    int* offs = (int*)wp;    wp += (size_t)(n + 1) * 4;
    int* csr_src = (int*)wp; wp += (size_t)E * 4;
    int* nlist = (int*)wp;   wp += (size_t)16 * n * 4;
    int* clsidx = (int*)wp;  wp += (size_t)n * 4;
    float* dis = (float*)wp; wp += (size_t)n * 4;
    float* inv = (float*)wp; wp += (size_t)n * 4;

    hipMemsetAsync(small0, 0, small_bytes, stream);
    hipMemsetAsync(clsidx, 0xFF, (size_t)n * 4, stream);

    // tiny precompute: W' = gcn_w @ mu_w, b' = gcn_b @ mu_w + mu_b, packed stage weights
    mm_kernel<0><<<DIM / 32, 256, 0, stream>>>(gcn_w, mu_w, nullptr, wprime, DIM);
    bprime_kernel<<<1, DIM, 0, stream>>>(gcn_b, mu_w, mu_b, bprime);
    pack_kernel<<<(PACK_TOTAL + 255) / 256, 256, 0, stream>>>(as_w, ua_w, ns_w, un_w, wpack);

    deg_count_kernel<<<(E + 255) / 256, 256, 0, stream>>>(dstv, degi, E);
    build_node_lists_kernel<<<(n + 255) / 256, 256, 0, stream>>>(gate, level, nlist, ncnt, clsidx, n);
    scan1_kernel<<<n / 1024, 1024, 0, stream>>>(degi, offs, bsum, dis, inv);
    scan2_kernel<<<1, 64, 0, stream>>>(bsum, n / 1024);
    scan3_kernel<<<n / 1024, 1024, 0, stream>>>(offs, bsum, n);
    csr_fill_kernel<<<(E + 255) / 256, 256, 0, stream>>>(srcv, dstv, offs, cursor, csr_src, E);

    // --- GCN encoder, algebra-folded: hs = agg(hs_init) @ W' + b' ---
    gcn_gather_kernel<<<4096, 256, 0, stream>>>(hs_init, dis, inv, offs, csr_src, x, n);
    mm_kernel<1><<<n / 32, 256, 0, stream>>>(x, wprime, bprime, hs, n);

    // --- level loop: 2 launches/level (fused commit+gather+update), 1 final commit ---
    for (int l = 1; l <= NLEV; l++) {
        const int cA = l - 1;
        const int cN = NLEV + l - 1;
        const int cNp = NLEV + l - 2;
        if (l == 1)
            and_stage_kernel<false><<<NB_STAGE, 256, 0, stream>>>(
                hs, tmpN, tmpA, offs, csr_src, nlist, ncnt, clsidx, wpack,
                as_b, ua_b, cA, -9, n);
        else
            and_stage_kernel<true><<<NB_STAGE, 256, 0, stream>>>(
                hs, tmpN, tmpA, offs, csr_src, nlist, ncnt, clsidx, wpack,
                as_b, ua_b, cA, cNp, n);
        not_stage_kernel<<<NB_STAGE, 256, 0, stream>>>(
            hs, tmpA, tmpN, offs, csr_src, nlist, ncnt, clsidx, wpack,
            ns_b, un_b, cA, cN, n);
    }
    commit_kernel<<<NB_STAGE, 256, 0, stream>>>(hs, tmpN, nlist, ncnt, 2 * NLEV - 1, n);

    // --- decoder: zs/zt dense (shared tile), then weighted gather ---
    float* zs = x;
    float* zt = x2;
    mm2_kernel<<<n / 32, 256, 0, stream>>>(hs, dec_ws_w, dec_wt_w, zs, zt, n);
    dec_gather_kernel<<<4096, 256, 0, stream>>>(zs, zt, offs, csr_src, hf_out, n);
}

// Round 14
// 502.825 us; speedup vs baseline: 1.2991x; 1.2991x over previous
//
#include <hip/hip_runtime.h>

#define DIM 128
#define NLEV 8
#define NB_STAGE 512           // stage-kernel grid; 4 waves/block -> 2048 wave-slots
#define NSLOT (NB_STAGE * 4)
#define CAP (2 * NSLOT)        // max nodes per class handled (expected ~1213)

// packed-weight offsets (float2 units): [k][jl] -> (W[k][jl], W[k][jl+64])
#define AS_OFF 0
#define UA_OFF 8192            // 256 rows -> 16384 float2
#define NS_OFF 24576
#define UN_OFF 32768
#define PACK_TOTAL 40960

__device__ __forceinline__ int cls_of(int g, int l) {
    if (l < 1 || l > NLEV) return -1;
    if (g == 1) return l - 1;
    if (g == 2) return NLEV + (l - 1);
    return -1;
}

// ---------------- prep kernels ----------------

__global__ void deg_count_kernel(const int* __restrict__ dstv, int* __restrict__ degi, int E) {
    int i = blockIdx.x * blockDim.x + threadIdx.x;
    if (i < E) atomicAdd(&degi[dstv[i]], 1);
}

// pack 4 stage weight matrices into float2-paired layout (coalesced staging)
__global__ void pack_kernel(const float* __restrict__ as_w, const float* __restrict__ ua_w,
                            const float* __restrict__ ns_w, const float* __restrict__ un_w,
                            float2* __restrict__ wpack) {
    int i = blockIdx.x * 256 + threadIdx.x;
    if (i >= PACK_TOTAL) return;
    const float* src;
    int local;
    if (i < UA_OFF)      { src = as_w; local = i; }
    else if (i < NS_OFF) { src = ua_w; local = i - UA_OFF; }
    else if (i < UN_OFF) { src = ns_w; local = i - NS_OFF; }
    else                 { src = un_w; local = i - UN_OFF; }
    int k = local >> 6, jl = local & 63;
    wpack[i] = make_float2(src[k * DIM + jl], src[k * DIM + jl + 64]);
}

// b' = gcn_b @ mu_w + mu_b   (folded GCN bias)
__global__ __launch_bounds__(DIM) void bprime_kernel(const float* __restrict__ gcn_b,
                                                     const float* __restrict__ mu_w,
                                                     const float* __restrict__ mu_b,
                                                     float* __restrict__ bp) {
    const int j = threadIdx.x;
    float acc = mu_b[j];
    for (int k = 0; k < DIM; k++) acc = fmaf(gcn_b[k], mu_w[k * DIM + j], acc);
    bp[j] = acc;
}

// ---- 3-kernel parallel exclusive scan (+ fused deg finalize) ----
__global__ __launch_bounds__(1024) void scan1_kernel(const int* __restrict__ degi,
                                                     int* __restrict__ offs,
                                                     int* __restrict__ bsum,
                                                     float* __restrict__ dis,
                                                     float* __restrict__ inv) {
    __shared__ int sh[1024];
    const int gid = blockIdx.x * 1024 + threadIdx.x;
    const int v = degi[gid];
    {
        float d = (float)v + 1.0f;
        dis[gid] = rsqrtf(d);
        inv[gid] = 1.0f / d;
    }
    sh[threadIdx.x] = v;
    __syncthreads();
    for (int off = 1; off < 1024; off <<= 1) {
        int t = (threadIdx.x >= off) ? sh[threadIdx.x - off] : 0;
        __syncthreads();
        sh[threadIdx.x] += t;
        __syncthreads();
    }
    offs[gid] = sh[threadIdx.x] - v;  // exclusive within block
    if (threadIdx.x == 1023) bsum[blockIdx.x] = sh[1023];
}

__global__ void scan2_kernel(int* __restrict__ bsum, int nb) {
    const int lane = threadIdx.x & 63;
    const int orig = (lane < nb) ? bsum[lane] : 0;
    int v = orig;
#pragma unroll
    for (int off = 1; off < 64; off <<= 1) {
        int t = __shfl_up(v, off, 64);
        if (lane >= off) v += t;
    }
    if (lane < nb) bsum[lane] = v - orig;  // exclusive base per block
    if (lane == nb - 1) bsum[nb] = v;      // grand total
}

__global__ __launch_bounds__(1024) void scan3_kernel(int* __restrict__ offs,
                                                     const int* __restrict__ bsum, int n) {
    const int gid = blockIdx.x * 1024 + threadIdx.x;
    offs[gid] += bsum[blockIdx.x];
    if (gid == n - 1) offs[n] = bsum[gridDim.x];
}

__global__ void csr_fill_kernel(const int* __restrict__ srcv, const int* __restrict__ dstv,
                                const int* __restrict__ offs, int* __restrict__ cursor,
                                int* __restrict__ csr_src, int E) {
    int i = blockIdx.x * blockDim.x + threadIdx.x;
    if (i >= E) return;
    int d = dstv[i];
    int pos = offs[d] + atomicAdd(&cursor[d], 1);
    csr_src[pos] = srcv[i];
}

// class lists + per-node packed (cls<<16)|idx lookup (clsidx pre-memset to -1)
__global__ __launch_bounds__(256) void build_node_lists_kernel(const int* __restrict__ gate,
                                                               const int* __restrict__ level,
                                                               int* __restrict__ nlist,
                                                               int* __restrict__ ncnt,
                                                               int* __restrict__ clsidx, int n) {
    __shared__ int lcnt[16];
    __shared__ int lbase[16];
    int t = threadIdx.x;
    int i = blockIdx.x * 256 + t;
    if (t < 16) lcnt[t] = 0;
    __syncthreads();
    int c = -1, lpos = 0;
    if (i < n) {
        c = cls_of(gate[i], level[i]);
        if (c >= 0) lpos = atomicAdd(&lcnt[c], 1);
    }
    __syncthreads();
    if (t < 16 && lcnt[t] > 0) lbase[t] = atomicAdd(&ncnt[t], lcnt[t]);
    __syncthreads();
    if (c >= 0) {
        int idx = lbase[c] + lpos;
        nlist[c * n + idx] = i;
        clsidx[i] = (c << 16) | idx;
    }
}

// ---------------- dense matmul: LDS-staged input tile, 32 rows/block ----------------
template <int BIAS>
__global__ __launch_bounds__(256) void mm_kernel(const float* __restrict__ in0,
                                                 const float* __restrict__ W,
                                                 const float* __restrict__ b,
                                                 float* __restrict__ out, int n) {
    const int R = 32;
    __shared__ float tile[R * DIM];
    const size_t row0 = (size_t)blockIdx.x * R;
    for (int t = threadIdx.x; t < R * DIM / 4; t += 256)
        ((float4*)tile)[t] = ((const float4*)(in0 + row0 * DIM))[t];
    __syncthreads();
    const int g = threadIdx.x >> 7;   // row-half 0/1
    const int j = threadIdx.x & 127;  // output column
    float acc[16];
#pragma unroll
    for (int r = 0; r < 16; r++) acc[r] = 0.f;
    const float* tb = tile + (g * 16) * DIM;
    for (int k = 0; k < DIM; k += 4) {
        float w0 = W[(k + 0) * DIM + j];
        float w1 = W[(k + 1) * DIM + j];
        float w2 = W[(k + 2) * DIM + j];
        float w3 = W[(k + 3) * DIM + j];
#pragma unroll
        for (int r = 0; r < 16; r++) {
            const float4 a = *reinterpret_cast<const float4*>(tb + r * DIM + k);
            acc[r] = fmaf(a.x, w0, acc[r]);
            acc[r] = fmaf(a.y, w1, acc[r]);
            acc[r] = fmaf(a.z, w2, acc[r]);
            acc[r] = fmaf(a.w, w3, acc[r]);
        }
    }
    float bias = BIAS ? b[j] : 0.f;
#pragma unroll
    for (int r = 0; r < 16; r++) out[(row0 + g * 16 + r) * DIM + j] = acc[r] + bias;
}

// fused decoder matmul: zs = in0 @ Ws, zt = in0 @ Wt (shared tile stage)
__global__ __launch_bounds__(256) void mm2_kernel(const float* __restrict__ in0,
                                                  const float* __restrict__ Ws,
                                                  const float* __restrict__ Wt,
                                                  float* __restrict__ zs,
                                                  float* __restrict__ zt, int n) {
    const int R = 32;
    __shared__ float tile[R * DIM];
    const size_t row0 = (size_t)blockIdx.x * R;
    for (int t = threadIdx.x; t < R * DIM / 4; t += 256)
        ((float4*)tile)[t] = ((const float4*)(in0 + row0 * DIM))[t];
    __syncthreads();
    const int g = threadIdx.x >> 7;
    const int j = threadIdx.x & 127;
    float accs[16], acct[16];
#pragma unroll
    for (int r = 0; r < 16; r++) { accs[r] = 0.f; acct[r] = 0.f; }
    const float* tb = tile + (g * 16) * DIM;
    for (int k = 0; k < DIM; k += 2) {
        float s0 = Ws[(k + 0) * DIM + j];
        float s1 = Ws[(k + 1) * DIM + j];
        float t0 = Wt[(k + 0) * DIM + j];
        float t1 = Wt[(k + 1) * DIM + j];
#pragma unroll
        for (int r = 0; r < 16; r++) {
            const float2 a = *reinterpret_cast<const float2*>(tb + r * DIM + k);
            accs[r] = fmaf(a.x, s0, accs[r]);
            accs[r] = fmaf(a.y, s1, accs[r]);
            acct[r] = fmaf(a.x, t0, acct[r]);
            acct[r] = fmaf(a.y, t1, acct[r]);
        }
    }
#pragma unroll
    for (int r = 0; r < 16; r++) {
        zs[(row0 + g * 16 + r) * DIM + j] = accs[r];
        zt[(row0 + g * 16 + r) * DIM + j] = acct[r];
    }
}

// ---------------- GCN aggregate as gather (bias folded into b') ----------------
__global__ __launch_bounds__(256) void gcn_gather_kernel(const float* __restrict__ x,
                                                         const float* __restrict__ dis,
                                                         const float* __restrict__ inv,
                                                         const int* __restrict__ offs,
                                                         const int* __restrict__ csr_src,
                                                         float* __restrict__ y, int n) {
    int slot = threadIdx.x >> 7, j = threadIdx.x & 127;
    for (int node = blockIdx.x * 2 + slot; node < n; node += gridDim.x * 2) {
        float di = dis[node];
        float acc = inv[node] * x[(size_t)node * DIM + j];
        int e1 = offs[node + 1];
        for (int p = offs[node]; p < e1; p++) {
            int s = csr_src[p];
            acc += di * dis[s] * x[(size_t)s * DIM + j];
        }
        y[(size_t)node * DIM + j] = acc;
    }
}

// ---------------- level-stage kernels: wave-per-node, LDS W + LDS row-broadcast ----------------

// copy a packed 64KB W (8192 float2) into LDS, fully coalesced float4
__device__ __forceinline__ void stage_pk(const float2* __restrict__ Wp, float2* __restrict__ W2) {
    const float4* s = (const float4*)Wp;
    float4* d = (float4*)W2;
    for (int t = threadIdx.x; t < 4096; t += 256) d[t] = s[t];
}

template <bool MERGE>
__device__ __forceinline__ const float* resolve_row(const float* __restrict__ base,
                                                    const float* __restrict__ tmp,
                                                    const int* __restrict__ clsidx,
                                                    int mcls, int s) {
    if (MERGE) {
        int cc = clsidx[s];
        if ((cc >> 16) == mcls && (cc & 0xFFFF) < CAP) return tmp + (size_t)(cc & 0xFFFF) * DIM;
    }
    return base + (size_t)s * DIM;
}

// load one edge pair's src rows into registers (global; issued early for latency hiding)
template <bool MERGE>
__device__ __forceinline__ void load_pair(const float* __restrict__ hs,
                                          const float* __restrict__ tmp,
                                          const int* __restrict__ clsidx, int mcls,
                                          const int* __restrict__ csr_src,
                                          int p, int e1, int lane,
                                          float& a00, float& a01, float& a10, float& a11) {
    const int s0 = csr_src[p];
    const int s1 = (p + 1 < e1) ? csr_src[p + 1] : s0;
    const float* r0 = resolve_row<MERGE>(hs, tmp, clsidx, mcls, s0);
    const float* r1 = resolve_row<MERGE>(hs, tmp, clsidx, mcls, s1);
    a00 = r0[lane]; a01 = r0[lane + 64];
    a10 = r1[lane]; a11 = r1[lane + 64];
}

// one 128-step matvec column-pair accumulation from LDS-broadcast row `ar` (128 floats)
__device__ __forceinline__ void mv128(const float* __restrict__ ar, const float2* __restrict__ W2,
                                      int lane, float& o0, float& o1) {
#pragma unroll 8
    for (int k = 0; k < 128; k += 4) {
        const float4 a = *(const float4*)&ar[k];  // uniform-address LDS broadcast
        float2 w;
        w = W2[(k + 0) * 64 + lane]; o0 = fmaf(a.x, w.x, o0); o1 = fmaf(a.x, w.y, o1);
        w = W2[(k + 1) * 64 + lane]; o0 = fmaf(a.y, w.x, o0); o1 = fmaf(a.y, w.y, o1);
        w = W2[(k + 2) * 64 + lane]; o0 = fmaf(a.z, w.x, o0); o1 = fmaf(a.z, w.y, o1);
        w = W2[(k + 3) * 64 + lane]; o0 = fmaf(a.w, w.x, o0); o1 = fmaf(a.w, w.y, o1);
    }
}

// AND stage: commit tmpN(cNp)->hs ; agg = gather(as_w, merged w/ tmpN) ;
//            tmpA[idx] = relu( cat[hs[node], agg] @ ua_w + ua_b )
template <bool MERGE>
__global__ __launch_bounds__(256) void and_stage_kernel(
        float* __restrict__ hs, const float* __restrict__ tmpN, float* __restrict__ tmpA,
        const int* __restrict__ offs, const int* __restrict__ csr_src,
        const int* __restrict__ nlist, const int* __restrict__ ncnt,
        const int* __restrict__ clsidx, const float2* __restrict__ wpack,
        const float* __restrict__ as_b, const float* __restrict__ ua_b,
        int cA, int cNp, int n) {
    const int cnt = min(ncnt[cA], CAP);
    const int cntp = MERGE ? min(ncnt[cNp], CAP) : 0;
    const int lim = max(cnt, cntp);
    if ((int)blockIdx.x * 4 >= lim) return;  // block-uniform early exit
    __shared__ float2 W2[128 * 64];
    __shared__ float arow[4][2][256];  // per-wave, per-slot row scratch (2 rows of 128)
    const int lane = threadIdx.x & 63;
    const int wv = threadIdx.x >> 6;
    const int gslot = (blockIdx.x << 2) | wv;

    // ---- early global loads (hide under W staging) ----
    bool act[2]; int nd[2], e0[2], e1[2];
#pragma unroll
    for (int it = 0; it < 2; it++) {
        const int idx = gslot + it * NSLOT;
        act[it] = idx < cnt;
        nd[it] = act[it] ? nlist[cA * n + idx] : 0;
        e0[it] = act[it] ? offs[nd[it]] : 0;
        e1[it] = act[it] ? offs[nd[it] + 1] : 0;
    }
    float h0[2] = {0.f, 0.f}, h1[2] = {0.f, 0.f};
#pragma unroll
    for (int it = 0; it < 2; it++) {
        if (act[it]) {  // cA rows are never written in this kernel -> pre-update value
            h0[it] = hs[(size_t)nd[it] * DIM + lane];
            h1[it] = hs[(size_t)nd[it] * DIM + lane + 64];
        }
    }
    float pa[2][4];
#pragma unroll
    for (int it = 0; it < 2; it++) {
        if (act[it] && e0[it] < e1[it])
            load_pair<MERGE>(hs, tmpN, clsidx, cNp, csr_src, e0[it], e1[it], lane,
                             pa[it][0], pa[it][1], pa[it][2], pa[it][3]);
    }
    // commit previous level's NOT updates (gathers read those rows via tmpN indirection)
    if (MERGE) {
        for (int idx = gslot; idx < cntp; idx += NSLOT) {
            const int node = nlist[cNp * n + idx];
            hs[(size_t)node * DIM + lane] = tmpN[(size_t)idx * DIM + lane];
            hs[(size_t)node * DIM + lane + 64] = tmpN[(size_t)idx * DIM + lane + 64];
        }
    }
    stage_pk(wpack + AS_OFF, W2);
    __syncthreads();

    // ---- gather: software-pipelined edge pairs, LDS row-broadcast matvec ----
    const float bj_as0 = as_b[lane], bj_as1 = as_b[lane + 64];
    float ag0[2] = {0.f, 0.f}, ag1[2] = {0.f, 0.f};
#pragma unroll
    for (int it = 0; it < 2; it++) {
        if (!act[it]) continue;
        float* ar = arow[wv][it];
        float a00 = pa[it][0], a01 = pa[it][1], a10 = pa[it][2], a11 = pa[it][3];
        for (int p = e0[it]; p < e1[it]; p += 2) {
            ar[lane] = a00; ar[64 + lane] = a01;
            ar[128 + lane] = a10; ar[192 + lane] = a11;
            const bool two = (p + 1 < e1[it]);
            float n00 = 0.f, n01 = 0.f, n10 = 0.f, n11 = 0.f;
            if (p + 2 < e1[it])  // prefetch next pair during this pair's k-loop
                load_pair<MERGE>(hs, tmpN, clsidx, cNp, csr_src, p + 2, e1[it], lane,
                                 n00, n01, n10, n11);
            float m00 = bj_as0, m01 = bj_as1, m10 = bj_as0, m11 = bj_as1;
#pragma unroll 8
            for (int k = 0; k < 128; k += 4) {
                const float4 a0 = *(const float4*)&ar[k];
                const float4 a1 = *(const float4*)&ar[128 + k];
                float2 w;
                w = W2[(k + 0) * 64 + lane];
                m00 = fmaf(a0.x, w.x, m00); m01 = fmaf(a0.x, w.y, m01);
                m10 = fmaf(a1.x, w.x, m10); m11 = fmaf(a1.x, w.y, m11);
                w = W2[(k + 1) * 64 + lane];
                m00 = fmaf(a0.y, w.x, m00); m01 = fmaf(a0.y, w.y, m01);
                m10 = fmaf(a1.y, w.x, m10); m11 = fmaf(a1.y, w.y, m11);
                w = W2[(k + 2) * 64 + lane];
                m00 = fmaf(a0.z, w.x, m00); m01 = fmaf(a0.z, w.y, m01);
                m10 = fmaf(a1.z, w.x, m10); m11 = fmaf(a1.z, w.y, m11);
                w = W2[(k + 3) * 64 + lane];
                m00 = fmaf(a0.w, w.x, m00); m01 = fmaf(a0.w, w.y, m01);
                m10 = fmaf(a1.w, w.x, m10); m11 = fmaf(a1.w, w.y, m11);
            }
            ag0[it] += fmaxf(m00, 0.f);
            ag1[it] += fmaxf(m01, 0.f);
            if (two) { ag0[it] += fmaxf(m10, 0.f); ag1[it] += fmaxf(m11, 0.f); }
            a00 = n00; a01 = n01; a10 = n10; a11 = n11;
        }
    }

    // ---- update: u = cat[h, agg] @ ua_w + ua_b, two staged halves ----
    float u0[2], u1[2];
    u0[0] = ua_b[lane]; u1[0] = ua_b[lane + 64];
    u0[1] = u0[0]; u1[1] = u1[0];
    __syncthreads();
    stage_pk(wpack + UA_OFF, W2);          // ua rows 0..127 (hs half)
    __syncthreads();
#pragma unroll
    for (int it = 0; it < 2; it++) {
        if (!act[it]) continue;
        float* ar = arow[wv][it];
        ar[lane] = h0[it]; ar[64 + lane] = h1[it];
        mv128(ar, W2, lane, u0[it], u1[it]);
    }
    __syncthreads();
    stage_pk(wpack + UA_OFF + 8192, W2);   // ua rows 128..255 (agg half)
    __syncthreads();
#pragma unroll
    for (int it = 0; it < 2; it++) {
        if (!act[it]) continue;
        float* ar = arow[wv][it];
        ar[lane] = ag0[it]; ar[64 + lane] = ag1[it];
        mv128(ar, W2, lane, u0[it], u1[it]);
        const int idx = gslot + it * NSLOT;
        tmpA[(size_t)idx * DIM + lane] = fmaxf(u0[it], 0.f);
        tmpA[(size_t)idx * DIM + lane + 64] = fmaxf(u1[it], 0.f);
    }
}

// NOT stage: commit tmpA(cA)->hs ; agg = gather(ns_w, merged w/ tmpA) ;
//            tmpN[idx] = tanh( agg @ un_w + un_b )
__global__ __launch_bounds__(256) void not_stage_kernel(
        float* __restrict__ hs, const float* __restrict__ tmpA, float* __restrict__ tmpN,
        const int* __restrict__ offs, const int* __restrict__ csr_src,
        const int* __restrict__ nlist, const int* __restrict__ ncnt,
        const int* __restrict__ clsidx, const float2* __restrict__ wpack,
        const float* __restrict__ ns_b, const float* __restrict__ un_b,
        int cA, int cN, int n) {
    const int cnt = min(ncnt[cN], CAP);
    const int cntA = min(ncnt[cA], CAP);
    const int lim = max(cnt, cntA);
    if ((int)blockIdx.x * 4 >= lim) return;
    __shared__ float2 W2[128 * 64];
    __shared__ float arow[4][2][256];
    const int lane = threadIdx.x & 63;
    const int wv = threadIdx.x >> 6;
    const int gslot = (blockIdx.x << 2) | wv;

    bool act[2]; int nd[2], e0[2], e1[2];
#pragma unroll
    for (int it = 0; it < 2; it++) {
        const int idx = gslot + it * NSLOT;
        act[it] = idx < cnt;
        nd[it] = act[it] ? nlist[cN * n + idx] : 0;
        e0[it] = act[it] ? offs[nd[it]] : 0;
        e1[it] = act[it] ? offs[nd[it] + 1] : 0;
    }
    float pa[2][4];
#pragma unroll
    for (int it = 0; it < 2; it++) {
        if (act[it] && e0[it] < e1[it])
            load_pair<true>(hs, tmpA, clsidx, cA, csr_src, e0[it], e1[it], lane,
                            pa[it][0], pa[it][1], pa[it][2], pa[it][3]);
    }
    // commit this level's AND updates
    for (int idx = gslot; idx < cntA; idx += NSLOT) {
        const int node = nlist[cA * n + idx];
        hs[(size_t)node * DIM + lane] = tmpA[(size_t)idx * DIM + lane];
        hs[(size_t)node * DIM + lane + 64] = tmpA[(size_t)idx * DIM + lane + 64];
    }
    stage_pk(wpack + NS_OFF, W2);
    __syncthreads();

    const float bj_ns0 = ns_b[lane], bj_ns1 = ns_b[lane + 64];
    float ag0[2] = {0.f, 0.f}, ag1[2] = {0.f, 0.f};
#pragma unroll
    for (int it = 0; it < 2; it++) {
        if (!act[it]) continue;
        float* ar = arow[wv][it];
        float a00 = pa[it][0], a01 = pa[it][1], a10 = pa[it][2], a11 = pa[it][3];
        for (int p = e0[it]; p < e1[it]; p += 2) {
            ar[lane] = a00; ar[64 + lane] = a01;
            ar[128 + lane] = a10; ar[192 + lane] = a11;
            const bool two = (p + 1 < e1[it]);
            float n00 = 0.f, n01 = 0.f, n10 = 0.f, n11 = 0.f;
            if (p + 2 < e1[it])
                load_pair<true>(hs, tmpA, clsidx, cA, csr_src, p + 2, e1[it], lane,
                                n00, n01, n10, n11);
            float m00 = bj_ns0, m01 = bj_ns1, m10 = bj_ns0, m11 = bj_ns1;
#pragma unroll 8
            for (int k = 0; k < 128; k += 4) {
                const float4 a0 = *(const float4*)&ar[k];
                const float4 a1 = *(const float4*)&ar[128 + k];
                float2 w;
                w = W2[(k + 0) * 64 + lane];
                m00 = fmaf(a0.x, w.x, m00); m01 = fmaf(a0.x, w.y, m01);
                m10 = fmaf(a1.x, w.x, m10); m11 = fmaf(a1.x, w.y, m11);
                w = W2[(k + 1) * 64 + lane];
                m00 = fmaf(a0.y, w.x, m00); m01 = fmaf(a0.y, w.y, m01);
                m10 = fmaf(a1.y, w.x, m10); m11 = fmaf(a1.y, w.y, m11);
                w = W2[(k + 2) * 64 + lane];
                m00 = fmaf(a0.z, w.x, m00); m01 = fmaf(a0.z, w.y, m01);
                m10 = fmaf(a1.z, w.x, m10); m11 = fmaf(a1.z, w.y, m11);
                w = W2[(k + 3) * 64 + lane];
                m00 = fmaf(a0.w, w.x, m00); m01 = fmaf(a0.w, w.y, m01);
                m10 = fmaf(a1.w, w.x, m10); m11 = fmaf(a1.w, w.y, m11);
            }
            ag0[it] += fmaxf(m00, 0.f);
            ag1[it] += fmaxf(m01, 0.f);
            if (two) { ag0[it] += fmaxf(m10, 0.f); ag1[it] += fmaxf(m11, 0.f); }
            a00 = n00; a01 = n01; a10 = n10; a11 = n11;
        }
    }

    float u0[2], u1[2];
    u0[0] = un_b[lane]; u1[0] = un_b[lane + 64];
    u0[1] = u0[0]; u1[1] = u1[0];
    __syncthreads();
    stage_pk(wpack + UN_OFF, W2);
    __syncthreads();
#pragma unroll
    for (int it = 0; it < 2; it++) {
        if (!act[it]) continue;
        float* ar = arow[wv][it];
        ar[lane] = ag0[it]; ar[64 + lane] = ag1[it];
        mv128(ar, W2, lane, u0[it], u1[it]);
        const int idx = gslot + it * NSLOT;
        tmpN[(size_t)idx * DIM + lane] = tanhf(u0[it]);
        tmpN[(size_t)idx * DIM + lane + 64] = tanhf(u1[it]);
    }
}

// final commit of last level's tmpN -> hs
__global__ __launch_bounds__(256) void commit_kernel(float* __restrict__ hs,
                                                     const float* __restrict__ tmp,
                                                     const int* __restrict__ nlist,
                                                     const int* __restrict__ ncnt,
                                                     int c, int n) {
    const int lane = threadIdx.x & 63;
    const int gslot = (blockIdx.x << 2) | (threadIdx.x >> 6);
    const int cnt = min(ncnt[c], CAP);
    for (int idx = gslot; idx < cnt; idx += NSLOT) {
        const int node = nlist[c * n + idx];
        hs[(size_t)node * DIM + lane] = tmp[(size_t)idx * DIM + lane];
        hs[(size_t)node * DIM + lane + 64] = tmp[(size_t)idx * DIM + lane + 64];
    }
}

// ---------------- decoder as gather (wave per node, deterministic) ----------------
__global__ __launch_bounds__(256) void dec_gather_kernel(const float* __restrict__ zs,
                                                         const float* __restrict__ zt,
                                                         const int* __restrict__ offs,
                                                         const int* __restrict__ csr_src,
                                                         float* __restrict__ hf_out, int n) {
    int w = threadIdx.x >> 6, lane = threadIdx.x & 63;
    for (int node = blockIdx.x * 4 + w; node < n; node += gridDim.x * 4) {
        float b0 = zt[(size_t)node * DIM + lane];
        float b1 = zt[(size_t)node * DIM + 64 + lane];
        float acc0 = 0.f, acc1 = 0.f;
        int e1 = offs[node + 1];
        for (int p = offs[node]; p < e1; p++) {
            int s = csr_src[p];
            float a0 = zs[(size_t)s * DIM + lane];
            float a1 = zs[(size_t)s * DIM + 64 + lane];
            float pd = a0 * b0 + a1 * b1;
#pragma unroll
            for (int off = 32; off > 0; off >>= 1) pd += __shfl_xor(pd, off, 64);
            float wg = 1.f / (1.f + __expf(-pd));
            acc0 += wg * a0;
            acc1 += wg * a1;
        }
        hf_out[(size_t)node * DIM + lane] = acc0;
        hf_out[(size_t)node * DIM + 64 + lane] = acc1;
    }
}

extern "C" void kernel_launch(void* const* d_in, const int* in_sizes, int n_in,
                              void* d_out, int out_size, void* d_ws, size_t ws_size,
                              hipStream_t stream) {
    const float* hs_init = (const float*)d_in[0];
    const int* ei = (const int*)d_in[1];
    const int* gate = (const int*)d_in[2];
    const int* level = (const int*)d_in[3];
    const float* gcn_w = (const float*)d_in[4];
    const float* gcn_b = (const float*)d_in[5];
    const float* mu_w = (const float*)d_in[6];
    const float* mu_b = (const float*)d_in[7];
    // ls_w/ls_b (8,9) dead (eval mode); af/nf (14..17) dead (level-loop hf never feeds hs;
    // decoder rebuilds hf from hs alone).
    const float* as_w = (const float*)d_in[10];
    const float* as_b = (const float*)d_in[11];
    const float* ns_w = (const float*)d_in[12];
    const float* ns_b = (const float*)d_in[13];
    const float* ua_w = (const float*)d_in[18];
    const float* ua_b = (const float*)d_in[19];
    const float* un_w = (const float*)d_in[20];
    const float* un_b = (const float*)d_in[21];
    const float* dec_ws_w = (const float*)d_in[22];
    const float* dec_wt_w = (const float*)d_in[23];

    const int n = in_sizes[0] / DIM;  // 32768
    const int E = in_sizes[1] / 2;    // 65536
    const int* srcv = ei;
    const int* dstv = ei + E;

    float* hs = (float*)d_out;             // [n, DIM]
    float* hf_out = hs + (size_t)n * DIM;  // [n, DIM]

    char* wp = (char*)d_ws;
    float* x = (float*)wp;      wp += (size_t)n * DIM * 4;     // gcn agg, later zs
    float* x2 = (float*)wp;     wp += (size_t)n * DIM * 4;     // zt
    float* tmpA = (float*)wp;   wp += (size_t)CAP * DIM * 4;   // AND-update staging
    float* tmpN = (float*)wp;   wp += (size_t)CAP * DIM * 4;   // NOT-update staging
    float2* wpack = (float2*)wp; wp += (size_t)PACK_TOTAL * 8; // packed stage weights
    float* wprime = (float*)wp; wp += (size_t)DIM * DIM * 4;   // gcn_w @ mu_w
    float* bprime = (float*)wp; wp += (size_t)DIM * 4;         // gcn_b @ mu_w + mu_b
    char* small0 = wp;
    int* degi = (int*)wp;   wp += (size_t)n * 4;
    int* cursor = (int*)wp; wp += (size_t)n * 4;
    int* ncnt = (int*)wp;   wp += 16 * 4;
    size_t small_bytes = (size_t)(wp - small0);
    int* bsum = (int*)wp;    wp += 64 * 4;
    int* offs = (int*)wp;    wp += (size_t)(n + 1) * 4;
    int* csr_src = (int*)wp; wp += (size_t)E * 4;
    int* nlist = (int*)wp;   wp += (size_t)16 * n * 4;
    int* clsidx = (int*)wp;  wp += (size_t)n * 4;
    float* dis = (float*)wp; wp += (size_t)n * 4;
    float* inv = (float*)wp; wp += (size_t)n * 4;

    hipMemsetAsync(small0, 0, small_bytes, stream);
    hipMemsetAsync(clsidx, 0xFF, (size_t)n * 4, stream);

    // tiny precompute: W' = gcn_w @ mu_w, b' = gcn_b @ mu_w + mu_b, packed stage weights
    mm_kernel<0><<<DIM / 32, 256, 0, stream>>>(gcn_w, mu_w, nullptr, wprime, DIM);
    bprime_kernel<<<1, DIM, 0, stream>>>(gcn_b, mu_w, mu_b, bprime);
    pack_kernel<<<(PACK_TOTAL + 255) / 256, 256, 0, stream>>>(as_w, ua_w, ns_w, un_w, wpack);

    deg_count_kernel<<<(E + 255) / 256, 256, 0, stream>>>(dstv, degi, E);
    build_node_lists_kernel<<<(n + 255) / 256, 256, 0, stream>>>(gate, level, nlist, ncnt, clsidx, n);
    scan1_kernel<<<n / 1024, 1024, 0, stream>>>(degi, offs, bsum, dis, inv);
    scan2_kernel<<<1, 64, 0, stream>>>(bsum, n / 1024);
    scan3_kernel<<<n / 1024, 1024, 0, stream>>>(offs, bsum, n);
    csr_fill_kernel<<<(E + 255) / 256, 256, 0, stream>>>(srcv, dstv, offs, cursor, csr_src, E);

    // --- GCN encoder, algebra-folded: hs = agg(hs_init) @ W' + b' ---
    gcn_gather_kernel<<<4096, 256, 0, stream>>>(hs_init, dis, inv, offs, csr_src, x, n);
    mm_kernel<1><<<n / 32, 256, 0, stream>>>(x, wprime, bprime, hs, n);

    // --- level loop: 2 launches/level (fused commit+gather+update), 1 final commit ---
    for (int l = 1; l <= NLEV; l++) {
        const int cA = l - 1;
        const int cN = NLEV + l - 1;
        const int cNp = NLEV + l - 2;
        if (l == 1)
            and_stage_kernel<false><<<NB_STAGE, 256, 0, stream>>>(
                hs, tmpN, tmpA, offs, csr_src, nlist, ncnt, clsidx, wpack,
                as_b, ua_b, cA, -9, n);
        else
            and_stage_kernel<true><<<NB_STAGE, 256, 0, stream>>>(
                hs, tmpN, tmpA, offs, csr_src, nlist, ncnt, clsidx, wpack,
                as_b, ua_b, cA, cNp, n);
        not_stage_kernel<<<NB_STAGE, 256, 0, stream>>>(
            hs, tmpA, tmpN, offs, csr_src, nlist, ncnt, clsidx, wpack,
            ns_b, un_b, cA, cN, n);
    }
    commit_kernel<<<NB_STAGE, 256, 0, stream>>>(hs, tmpN, nlist, ncnt, 2 * NLEV - 1, n);

    // --- decoder: zs/zt dense (shared tile), then weighted gather ---
    float* zs = x;
    float* zt = x2;
    mm2_kernel<<<n / 32, 256, 0, stream>>>(hs, dec_ws_w, dec_wt_w, zs, zt, n);
    dec_gather_kernel<<<4096, 256, 0, stream>>>(zs, zt, offs, csr_src, hf_out, n);
}